// Round 4
// baseline (675.917 us; speedup 1.0000x reference)
//
#include <hip/hip_runtime.h>

#define N_NODES 50000
#define N_EDGES 1600000
#define D_FEAT 512
#define FILTERS 256
#define NUM_CLASSES 16

typedef __bf16 bf16x8 __attribute__((ext_vector_type(8)));
typedef float f32x4 __attribute__((ext_vector_type(4)));
typedef _Float16 half4 __attribute__((ext_vector_type(4)));

#define GLOAD_LDS16(g, l)                                                  \
  __builtin_amdgcn_global_load_lds(                                        \
      (const __attribute__((address_space(1))) unsigned int*)(g),          \
      (__attribute__((address_space(3))) unsigned int*)(l), 16, 0, 0)

// ---------------------------------------------------------------------------
// Split W1 [512,256] fp32 -> W1^T hi/lo bf16 [256,512]
// ---------------------------------------------------------------------------
__global__ __launch_bounds__(256) void split_w1_kernel(
    const float* __restrict__ W1, __bf16* __restrict__ Wth,
    __bf16* __restrict__ Wtl) {
  const int idx = blockIdx.x * 256 + threadIdx.x;  // 131072 total
  const int k = idx >> 8;
  const int n = idx & 255;
  const float v = W1[idx];
  const __bf16 h = (__bf16)v;
  const __bf16 l = (__bf16)(v - (float)h);
  Wth[n * D_FEAT + k] = h;
  Wtl[n * D_FEAT + k] = l;
}

// ---------------------------------------------------------------------------
// GEMM1 via MFMA bf16x3: XW1 = X @ W1, fp32-accurate, output stored fp16.
// 128x128 tile, BK=32, 4 waves 2x2, each wave 4x4 MFMA 16x16x32 tiles.
// ---------------------------------------------------------------------------
__global__ __launch_bounds__(256) void gemm1_mfma_kernel(
    const float* __restrict__ A,    // [M,512] fp32
    const __bf16* __restrict__ Bh,  // [256,512] W1^T hi
    const __bf16* __restrict__ Bl,  // [256,512] W1^T lo
    _Float16* __restrict__ C) {     // [M,256] fp16
  const int K = D_FEAT;
  __shared__ __bf16 sAh[128 * 32];
  __shared__ __bf16 sAl[128 * 32];
  __shared__ __bf16 sBh[128 * 32];
  __shared__ __bf16 sBl[128 * 32];

  const int tid = threadIdx.x;
  const int wave = tid >> 6;
  const int lane = tid & 63;
  const int wm = (wave >> 1) * 64;
  const int wn = (wave & 1) * 64;
  const int m0 = blockIdx.x * 128;
  const int n0 = blockIdx.y * 128;

  const int arow = tid >> 1;
  const int aks = (tid & 1) * 16;
  int am = m0 + arow;
  if (am >= N_NODES) am = N_NODES - 1;
  const float* aptr = A + (size_t)am * K + aks;

  const int lr = lane >> 2;
  const int lc = (lane & 3) * 8;
  const int fm = lane & 15;
  const int fq = lane >> 4;

  f32x4 acc[4][4] = {};

  for (int k0 = 0; k0 < K; k0 += 32) {
    const float4* ap = (const float4*)(aptr + k0);
    const float4 a0 = ap[0], a1 = ap[1], a2 = ap[2], a3 = ap[3];

    __syncthreads();

#pragma unroll
    for (int i = 0; i < 2; ++i) {
      const int row = wave * 32 + i * 16;
      GLOAD_LDS16(Bh + (size_t)(n0 + row + lr) * K + k0 + lc, sBh + row * 32);
      GLOAD_LDS16(Bl + (size_t)(n0 + row + lr) * K + k0 + lc, sBl + row * 32);
    }

    float va[16] = {a0.x, a0.y, a0.z, a0.w, a1.x, a1.y, a1.z, a1.w,
                    a2.x, a2.y, a2.z, a2.w, a3.x, a3.y, a3.z, a3.w};
    __bf16 hh[16], ll[16];
#pragma unroll
    for (int i = 0; i < 16; ++i) {
      const __bf16 h = (__bf16)va[i];
      hh[i] = h;
      ll[i] = (__bf16)(va[i] - (float)h);
    }
    *(bf16x8*)(sAh + arow * 32 + aks) = *(bf16x8*)&hh[0];
    *(bf16x8*)(sAh + arow * 32 + aks + 8) = *(bf16x8*)&hh[8];
    *(bf16x8*)(sAl + arow * 32 + aks) = *(bf16x8*)&ll[0];
    *(bf16x8*)(sAl + arow * 32 + aks + 8) = *(bf16x8*)&ll[8];

    __syncthreads();

    bf16x8 fah[4], fal[4], fbh[4], fbl[4];
#pragma unroll
    for (int t = 0; t < 4; ++t) {
      const int moff = (wm + t * 16 + fm) * 32 + fq * 8;
      fah[t] = *(const bf16x8*)(sAh + moff);
      fal[t] = *(const bf16x8*)(sAl + moff);
      const int noff = (wn + t * 16 + fm) * 32 + fq * 8;
      fbh[t] = *(const bf16x8*)(sBh + noff);
      fbl[t] = *(const bf16x8*)(sBl + noff);
    }
#pragma unroll
    for (int i = 0; i < 4; ++i)
#pragma unroll
      for (int j = 0; j < 4; ++j)
        acc[i][j] = __builtin_amdgcn_mfma_f32_16x16x32_bf16(fah[i], fbh[j],
                                                            acc[i][j], 0, 0, 0);
#pragma unroll
    for (int i = 0; i < 4; ++i)
#pragma unroll
      for (int j = 0; j < 4; ++j)
        acc[i][j] = __builtin_amdgcn_mfma_f32_16x16x32_bf16(fah[i], fbl[j],
                                                            acc[i][j], 0, 0, 0);
#pragma unroll
    for (int i = 0; i < 4; ++i)
#pragma unroll
      for (int j = 0; j < 4; ++j)
        acc[i][j] = __builtin_amdgcn_mfma_f32_16x16x32_bf16(fal[i], fbh[j],
                                                            acc[i][j], 0, 0, 0);
  }

#pragma unroll
  for (int ti = 0; ti < 4; ++ti) {
#pragma unroll
    for (int r = 0; r < 4; ++r) {
      const int m = m0 + wm + ti * 16 + fq * 4 + r;
      if (m < N_NODES) {
#pragma unroll
        for (int tj = 0; tj < 4; ++tj) {
          const int n = n0 + wn + tj * 16 + fm;
          C[(size_t)m * FILTERS + n] = (_Float16)acc[ti][tj][r];
        }
      }
    }
  }
}

// ---------------------------------------------------------------------------
// CSR build: histogram of dst degrees
// ---------------------------------------------------------------------------
__global__ __launch_bounds__(256) void hist_kernel(const int* __restrict__ edst,
                                                   int* __restrict__ deg) {
  const int e = blockIdx.x * 256 + threadIdx.x;
  if (e < N_EDGES) atomicAdd(&deg[edst[e]], 1);
}

// ---------------------------------------------------------------------------
// Parallel exclusive scan
// ---------------------------------------------------------------------------
#define SCAN_NB 196
__global__ __launch_bounds__(256) void scan_blocks_kernel(
    const int* __restrict__ deg, int* __restrict__ row_ptr,
    int* __restrict__ bsum) {
  __shared__ int s[256];
  const int i = blockIdx.x * 256 + threadIdx.x;
  const int v = (i < N_NODES) ? deg[i] : 0;
  s[threadIdx.x] = v;
  __syncthreads();
  for (int off = 1; off < 256; off <<= 1) {
    const int t = (threadIdx.x >= off) ? s[threadIdx.x - off] : 0;
    __syncthreads();
    s[threadIdx.x] += t;
    __syncthreads();
  }
  if (i < N_NODES) row_ptr[i] = s[threadIdx.x] - v;
  if (threadIdx.x == 255) bsum[blockIdx.x] = s[255];
}

__global__ __launch_bounds__(256) void scan_sums_kernel(int* __restrict__ bsum) {
  __shared__ int s[256];
  const int v = (threadIdx.x < SCAN_NB) ? bsum[threadIdx.x] : 0;
  s[threadIdx.x] = v;
  __syncthreads();
  for (int off = 1; off < 256; off <<= 1) {
    const int t = (threadIdx.x >= off) ? s[threadIdx.x - off] : 0;
    __syncthreads();
    s[threadIdx.x] += t;
    __syncthreads();
  }
  if (threadIdx.x < SCAN_NB) bsum[threadIdx.x] = s[threadIdx.x] - v;
}

__global__ __launch_bounds__(256) void scan_add_kernel(
    int* __restrict__ row_ptr, const int* __restrict__ bsum,
    int* __restrict__ cursor) {
  const int i = blockIdx.x * 256 + threadIdx.x;
  if (i < N_NODES) {
    const int r = row_ptr[i] + bsum[blockIdx.x];
    row_ptr[i] = r;
    cursor[i] = r;
  }
  if (i == 0) row_ptr[N_NODES] = N_EDGES;
}

// ---------------------------------------------------------------------------
// Fill: permute edges into dst-sorted order
// ---------------------------------------------------------------------------
__global__ __launch_bounds__(256) void fill_kernel(
    const int* __restrict__ esrc, const int* __restrict__ edst,
    const float* __restrict__ ew, int* __restrict__ cursor,
    int2* __restrict__ meta) {
  const int e = blockIdx.x * 256 + threadIdx.x;
  if (e >= N_EDGES) return;
  const int d = edst[e];
  const int pos = atomicAdd(&cursor[d], 1);
  meta[pos] = make_int2(esrc[e], __float_as_int(ew[e]));
}

// ---------------------------------------------------------------------------
// Fused gather1 + relu + gemm2:
//   h1 = sum_e w_e * xw1[src_e]  (fp16 rows, fp32 accum, in registers)
//   h2[node] = relu(h1) @ W2     (W2 L1-resident; butterfly + LDS reduce)
// One wave per node, lane owns feats [4*lane, 4*lane+4).
// ---------------------------------------------------------------------------
__global__ __launch_bounds__(256) void gather1_gemm2_kernel(
    const _Float16* __restrict__ xw1, const int* __restrict__ row_ptr,
    const int2* __restrict__ meta, const float* __restrict__ W2,
    float* __restrict__ h2) {
  __shared__ float red[4][16][17];
  const int wave = threadIdx.x >> 6;
  const int lane = threadIdx.x & 63;
  const int node = blockIdx.x * 4 + wave;
  const int beg = row_ptr[node];
  const int end = row_ptr[node + 1];

  float4 acc = make_float4(0.f, 0.f, 0.f, 0.f);
  for (int j = beg; j < end; ++j) {
    const int2 m = meta[j];
    const float w = __int_as_float(m.y);
    const half4 v = ((const half4*)(xw1 + (size_t)m.x * FILTERS))[lane];
    acc.x = fmaf(w, (float)v[0], acc.x);
    acc.y = fmaf(w, (float)v[1], acc.y);
    acc.z = fmaf(w, (float)v[2], acc.z);
    acc.w = fmaf(w, (float)v[3], acc.w);
  }

  // relu
  float r[4] = {fmaxf(acc.x, 0.f), fmaxf(acc.y, 0.f), fmaxf(acc.z, 0.f),
                fmaxf(acc.w, 0.f)};

  // per-lane partials over its 4 k's for all 16 classes (W2 is L1-resident)
  float p[16] = {};
#pragma unroll
  for (int j = 0; j < 4; ++j) {
    const int k = lane * 4 + j;
    const float4* wr = (const float4*)(W2 + (size_t)k * NUM_CLASSES);
#pragma unroll
    for (int c4 = 0; c4 < 4; ++c4) {
      const float4 wv = wr[c4];
      p[c4 * 4 + 0] = fmaf(r[j], wv.x, p[c4 * 4 + 0]);
      p[c4 * 4 + 1] = fmaf(r[j], wv.y, p[c4 * 4 + 1]);
      p[c4 * 4 + 2] = fmaf(r[j], wv.z, p[c4 * 4 + 2]);
      p[c4 * 4 + 3] = fmaf(r[j], wv.w, p[c4 * 4 + 3]);
    }
  }

  // butterfly: reduce over lane^32, lane^16 -> lanes 0..15 hold group sums
#pragma unroll
  for (int off = 32; off >= 16; off >>= 1)
#pragma unroll
    for (int i = 0; i < 16; ++i) p[i] += __shfl_xor(p[i], off, 64);

  // LDS transpose-reduce (17-padded, conflict-free), wave-private region
  if (lane < 16) {
#pragma unroll
    for (int i = 0; i < 16; ++i) red[wave][lane][i] = p[i];
  }
  // wave-internal LDS write->read: lockstep within wave, waitcnt by compiler
  if (lane < 16) {
    float sum = 0.f;
#pragma unroll
    for (int i = 0; i < 16; ++i) sum += red[wave][i][lane];
    h2[(size_t)node * NUM_CLASSES + lane] = sum;
  }
}

// ---------------------------------------------------------------------------
// Gather2 + softmax fused.
// ---------------------------------------------------------------------------
__global__ __launch_bounds__(256) void gather2_softmax_kernel(
    const float* __restrict__ h2, const int* __restrict__ row_ptr,
    const int2* __restrict__ meta, float* __restrict__ out) {
  const int g = threadIdx.x >> 4;
  const int c = threadIdx.x & 15;
  const int node = blockIdx.x * 16 + g;
  const int beg = row_ptr[node];
  const int end = row_ptr[node + 1];
  float acc = 0.f;
  for (int j = beg; j < end; ++j) {
    const int2 m = meta[j];
    acc = fmaf(__int_as_float(m.y), h2[(size_t)m.x * NUM_CLASSES + c], acc);
  }
  float mx = acc;
#pragma unroll
  for (int off = 8; off >= 1; off >>= 1) mx = fmaxf(mx, __shfl_xor(mx, off, 16));
  const float e = __expf(acc - mx);
  float s = e;
#pragma unroll
  for (int off = 8; off >= 1; off >>= 1) s += __shfl_xor(s, off, 16);
  out[(size_t)node * NUM_CLASSES + c] = e / s;
}

extern "C" void kernel_launch(void* const* d_in, const int* in_sizes, int n_in,
                              void* d_out, int out_size, void* d_ws,
                              size_t ws_size, hipStream_t stream) {
  const float* x = (const float*)d_in[0];
  const float* W1 = (const float*)d_in[1];
  const float* W2 = (const float*)d_in[2];
  const float* ew = (const float*)d_in[3];
  const int* esrc = (const int*)d_in[4];
  const int* edst = (const int*)d_in[5];
  float* out = (float*)d_out;

  _Float16* xw1 = (_Float16*)d_ws;                             // 12.8M fp16
  float* h2 = (float*)(xw1 + (size_t)N_NODES * FILTERS);       // 800K f32
  int* row_ptr = (int*)(h2 + (size_t)N_NODES * NUM_CLASSES);   // 50001
  int* cursor = row_ptr + (N_NODES + 1);                       // 50000
  int* deg = cursor + N_NODES;                                 // 50000
  int2* meta = (int2*)(((uintptr_t)(deg + N_NODES) + 15) & ~(uintptr_t)15);
  __bf16* w1th = (__bf16*)(meta + N_EDGES);                    // 131072 bf16
  __bf16* w1tl = w1th + D_FEAT * FILTERS;                      // 131072 bf16
  int* bsum = (int*)(w1tl + D_FEAT * FILTERS);                 // 196 ints

  // --- CSR build (dst-sorted) ---
  hipMemsetAsync(deg, 0, N_NODES * sizeof(int), stream);
  hist_kernel<<<(N_EDGES + 255) / 256, 256, 0, stream>>>(edst, deg);
  scan_blocks_kernel<<<SCAN_NB, 256, 0, stream>>>(deg, row_ptr, bsum);
  scan_sums_kernel<<<1, 256, 0, stream>>>(bsum);
  scan_add_kernel<<<SCAN_NB, 256, 0, stream>>>(row_ptr, bsum, cursor);
  fill_kernel<<<(N_EDGES + 255) / 256, 256, 0, stream>>>(esrc, edst, ew,
                                                         cursor, meta);

  // --- Layer 1 ---
  split_w1_kernel<<<(D_FEAT * FILTERS) / 256, 256, 0, stream>>>(W1, w1th, w1tl);
  dim3 g1((N_NODES + 127) / 128, FILTERS / 128);
  gemm1_mfma_kernel<<<g1, 256, 0, stream>>>(x, w1th, w1tl, xw1);

  // --- Fused propagate+relu+dense2 ---
  gather1_gemm2_kernel<<<N_NODES / 4, 256, 0, stream>>>(xw1, row_ptr, meta, W2,
                                                        h2);

  // --- Layer 2 propagate + softmax ---
  gather2_softmax_kernel<<<N_NODES / 16, 256, 0, stream>>>(h2, row_ptr, meta,
                                                           out);
}

// Round 5
// 659.356 us; speedup vs baseline: 1.0251x; 1.0251x over previous
//
#include <hip/hip_runtime.h>

#define N_NODES 50000
#define N_EDGES 1600000
#define D_FEAT 512
#define FILTERS 256
#define NUM_CLASSES 16

typedef __bf16 bf16x8 __attribute__((ext_vector_type(8)));
typedef float f32x4 __attribute__((ext_vector_type(4)));
typedef _Float16 half8 __attribute__((ext_vector_type(8)));

#define GLOAD_LDS16(g, l)                                                  \
  __builtin_amdgcn_global_load_lds(                                        \
      (const __attribute__((address_space(1))) unsigned int*)(g),          \
      (__attribute__((address_space(3))) unsigned int*)(l), 16, 0, 0)

// ---------------------------------------------------------------------------
// Split W1 [512,256] fp32 -> W1^T hi/lo bf16 [256,512]
// ---------------------------------------------------------------------------
__global__ __launch_bounds__(256) void split_w1_kernel(
    const float* __restrict__ W1, __bf16* __restrict__ Wth,
    __bf16* __restrict__ Wtl) {
  const int idx = blockIdx.x * 256 + threadIdx.x;
  const int k = idx >> 8;
  const int n = idx & 255;
  const float v = W1[idx];
  const __bf16 h = (__bf16)v;
  const __bf16 l = (__bf16)(v - (float)h);
  Wth[n * D_FEAT + k] = h;
  Wtl[n * D_FEAT + k] = l;
}

// ---------------------------------------------------------------------------
// GEMM1 via MFMA bf16x3: XW1 = X @ W1, fp32-accurate, output stored fp16.
// ---------------------------------------------------------------------------
__global__ __launch_bounds__(256) void gemm1_mfma_kernel(
    const float* __restrict__ A, const __bf16* __restrict__ Bh,
    const __bf16* __restrict__ Bl, _Float16* __restrict__ C) {
  const int K = D_FEAT;
  __shared__ __bf16 sAh[128 * 32];
  __shared__ __bf16 sAl[128 * 32];
  __shared__ __bf16 sBh[128 * 32];
  __shared__ __bf16 sBl[128 * 32];

  const int tid = threadIdx.x;
  const int wave = tid >> 6;
  const int lane = tid & 63;
  const int wm = (wave >> 1) * 64;
  const int wn = (wave & 1) * 64;
  const int m0 = blockIdx.x * 128;
  const int n0 = blockIdx.y * 128;

  const int arow = tid >> 1;
  const int aks = (tid & 1) * 16;
  int am = m0 + arow;
  if (am >= N_NODES) am = N_NODES - 1;
  const float* aptr = A + (size_t)am * K + aks;

  const int lr = lane >> 2;
  const int lc = (lane & 3) * 8;
  const int fm = lane & 15;
  const int fq = lane >> 4;

  f32x4 acc[4][4] = {};

  for (int k0 = 0; k0 < K; k0 += 32) {
    const float4* ap = (const float4*)(aptr + k0);
    const float4 a0 = ap[0], a1 = ap[1], a2 = ap[2], a3 = ap[3];

    __syncthreads();

#pragma unroll
    for (int i = 0; i < 2; ++i) {
      const int row = wave * 32 + i * 16;
      GLOAD_LDS16(Bh + (size_t)(n0 + row + lr) * K + k0 + lc, sBh + row * 32);
      GLOAD_LDS16(Bl + (size_t)(n0 + row + lr) * K + k0 + lc, sBl + row * 32);
    }

    float va[16] = {a0.x, a0.y, a0.z, a0.w, a1.x, a1.y, a1.z, a1.w,
                    a2.x, a2.y, a2.z, a2.w, a3.x, a3.y, a3.z, a3.w};
    __bf16 hh[16], ll[16];
#pragma unroll
    for (int i = 0; i < 16; ++i) {
      const __bf16 h = (__bf16)va[i];
      hh[i] = h;
      ll[i] = (__bf16)(va[i] - (float)h);
    }
    *(bf16x8*)(sAh + arow * 32 + aks) = *(bf16x8*)&hh[0];
    *(bf16x8*)(sAh + arow * 32 + aks + 8) = *(bf16x8*)&hh[8];
    *(bf16x8*)(sAl + arow * 32 + aks) = *(bf16x8*)&ll[0];
    *(bf16x8*)(sAl + arow * 32 + aks + 8) = *(bf16x8*)&ll[8];

    __syncthreads();

    bf16x8 fah[4], fal[4], fbh[4], fbl[4];
#pragma unroll
    for (int t = 0; t < 4; ++t) {
      const int moff = (wm + t * 16 + fm) * 32 + fq * 8;
      fah[t] = *(const bf16x8*)(sAh + moff);
      fal[t] = *(const bf16x8*)(sAl + moff);
      const int noff = (wn + t * 16 + fm) * 32 + fq * 8;
      fbh[t] = *(const bf16x8*)(sBh + noff);
      fbl[t] = *(const bf16x8*)(sBl + noff);
    }
#pragma unroll
    for (int i = 0; i < 4; ++i)
#pragma unroll
      for (int j = 0; j < 4; ++j)
        acc[i][j] = __builtin_amdgcn_mfma_f32_16x16x32_bf16(fah[i], fbh[j],
                                                            acc[i][j], 0, 0, 0);
#pragma unroll
    for (int i = 0; i < 4; ++i)
#pragma unroll
      for (int j = 0; j < 4; ++j)
        acc[i][j] = __builtin_amdgcn_mfma_f32_16x16x32_bf16(fah[i], fbl[j],
                                                            acc[i][j], 0, 0, 0);
#pragma unroll
    for (int i = 0; i < 4; ++i)
#pragma unroll
      for (int j = 0; j < 4; ++j)
        acc[i][j] = __builtin_amdgcn_mfma_f32_16x16x32_bf16(fal[i], fbh[j],
                                                            acc[i][j], 0, 0, 0);
  }

#pragma unroll
  for (int ti = 0; ti < 4; ++ti) {
#pragma unroll
    for (int r = 0; r < 4; ++r) {
      const int m = m0 + wm + ti * 16 + fq * 4 + r;
      if (m < N_NODES) {
#pragma unroll
        for (int tj = 0; tj < 4; ++tj) {
          const int n = n0 + wn + tj * 16 + fm;
          C[(size_t)m * FILTERS + n] = (_Float16)acc[ti][tj][r];
        }
      }
    }
  }
}

// ---------------------------------------------------------------------------
// CSR build
// ---------------------------------------------------------------------------
__global__ __launch_bounds__(256) void hist_kernel(const int* __restrict__ edst,
                                                   int* __restrict__ deg) {
  const int e = blockIdx.x * 256 + threadIdx.x;
  if (e < N_EDGES) atomicAdd(&deg[edst[e]], 1);
}

#define SCAN_NB 196
__global__ __launch_bounds__(256) void scan_blocks_kernel(
    const int* __restrict__ deg, int* __restrict__ row_ptr,
    int* __restrict__ bsum) {
  __shared__ int s[256];
  const int i = blockIdx.x * 256 + threadIdx.x;
  const int v = (i < N_NODES) ? deg[i] : 0;
  s[threadIdx.x] = v;
  __syncthreads();
  for (int off = 1; off < 256; off <<= 1) {
    const int t = (threadIdx.x >= off) ? s[threadIdx.x - off] : 0;
    __syncthreads();
    s[threadIdx.x] += t;
    __syncthreads();
  }
  if (i < N_NODES) row_ptr[i] = s[threadIdx.x] - v;
  if (threadIdx.x == 255) bsum[blockIdx.x] = s[255];
}

__global__ __launch_bounds__(256) void scan_sums_kernel(int* __restrict__ bsum) {
  __shared__ int s[256];
  const int v = (threadIdx.x < SCAN_NB) ? bsum[threadIdx.x] : 0;
  s[threadIdx.x] = v;
  __syncthreads();
  for (int off = 1; off < 256; off <<= 1) {
    const int t = (threadIdx.x >= off) ? s[threadIdx.x - off] : 0;
    __syncthreads();
    s[threadIdx.x] += t;
    __syncthreads();
  }
  if (threadIdx.x < SCAN_NB) bsum[threadIdx.x] = s[threadIdx.x] - v;
}

__global__ __launch_bounds__(256) void scan_add_kernel(
    int* __restrict__ row_ptr, const int* __restrict__ bsum,
    int* __restrict__ cursor) {
  const int i = blockIdx.x * 256 + threadIdx.x;
  if (i < N_NODES) {
    const int r = row_ptr[i] + bsum[blockIdx.x];
    row_ptr[i] = r;
    cursor[i] = r;
  }
  if (i == 0) row_ptr[N_NODES] = N_EDGES;
}

__global__ __launch_bounds__(256) void fill_kernel(
    const int* __restrict__ esrc, const int* __restrict__ edst,
    const float* __restrict__ ew, int* __restrict__ cursor,
    int2* __restrict__ meta) {
  const int e = blockIdx.x * 256 + threadIdx.x;
  if (e >= N_EDGES) return;
  const int d = edst[e];
  const int pos = atomicAdd(&cursor[d], 1);
  meta[pos] = make_int2(esrc[e], __float_as_int(ew[e]));
}

// ---------------------------------------------------------------------------
// Fused gather1 + relu + gemm2, 4 edges in flight per wave.
// Wave splits into two 32-lane halves; each half owns one edge per step
// (lane covers 8 fp16 feats = 16 B); explicit unroll x2.
// ---------------------------------------------------------------------------
__global__ __launch_bounds__(256) void gather1_gemm2_kernel(
    const _Float16* __restrict__ xw1, const int* __restrict__ row_ptr,
    const int2* __restrict__ meta, const float* __restrict__ W2,
    float* __restrict__ h2) {
  __shared__ float red[4][16][17];
  const int wave = threadIdx.x >> 6;
  const int lane = threadIdx.x & 63;
  const int half = lane >> 5;  // which edge slot
  const int fl = lane & 31;    // feature lane: feats [8*fl, 8*fl+8)
  const int node = blockIdx.x * 4 + wave;
  const int beg = row_ptr[node];
  const int end = row_ptr[node + 1];

  float acc[8] = {};
  for (int it = beg; it < end; it += 4) {
    const int e0 = it + half;
    const int e1 = it + 2 + half;
    int2 m0 = make_int2(0, 0), m1 = make_int2(0, 0);
    if (e0 < end) m0 = meta[e0];
    if (e1 < end) m1 = meta[e1];
    const float w0 = __int_as_float(m0.y);
    const float w1 = __int_as_float(m1.y);
    const half8 v0 = ((const half8*)(xw1 + (size_t)m0.x * FILTERS))[fl];
    const half8 v1 = ((const half8*)(xw1 + (size_t)m1.x * FILTERS))[fl];
#pragma unroll
    for (int i = 0; i < 8; ++i) acc[i] = fmaf(w0, (float)v0[i], acc[i]);
#pragma unroll
    for (int i = 0; i < 8; ++i) acc[i] = fmaf(w1, (float)v1[i], acc[i]);
  }

  // merge the two halves, then ReLU
#pragma unroll
  for (int i = 0; i < 8; ++i) {
    acc[i] += __shfl_xor(acc[i], 32, 64);
    acc[i] = fmaxf(acc[i], 0.f);
  }

  // gemm2 partials: lane's k = 8*fl + i; halves duplicate -> exact *0.5 later
  float p[16] = {};
#pragma unroll
  for (int i = 0; i < 8; ++i) {
    const float4* wr = (const float4*)(W2 + (size_t)(fl * 8 + i) * NUM_CLASSES);
#pragma unroll
    for (int c4 = 0; c4 < 4; ++c4) {
      const float4 wv = wr[c4];
      p[c4 * 4 + 0] = fmaf(acc[i], wv.x, p[c4 * 4 + 0]);
      p[c4 * 4 + 1] = fmaf(acc[i], wv.y, p[c4 * 4 + 1]);
      p[c4 * 4 + 2] = fmaf(acc[i], wv.z, p[c4 * 4 + 2]);
      p[c4 * 4 + 3] = fmaf(acc[i], wv.w, p[c4 * 4 + 3]);
    }
  }

#pragma unroll
  for (int off = 32; off >= 16; off >>= 1)
#pragma unroll
    for (int i = 0; i < 16; ++i) p[i] += __shfl_xor(p[i], off, 64);

  if (lane < 16) {
#pragma unroll
    for (int i = 0; i < 16; ++i) red[wave][lane][i] = p[i];
  }
  if (lane < 16) {
    float sum = 0.f;
#pragma unroll
    for (int i = 0; i < 16; ++i) sum += red[wave][i][lane];
    h2[(size_t)node * NUM_CLASSES + lane] = 0.5f * sum;
  }
}

// ---------------------------------------------------------------------------
// Gather2 + softmax: one wave per node, 4 edge slots x 16 classes,
// unroll x2 -> 8 edges in flight.
// ---------------------------------------------------------------------------
__global__ __launch_bounds__(256) void gather2_softmax_kernel(
    const float* __restrict__ h2, const int* __restrict__ row_ptr,
    const int2* __restrict__ meta, float* __restrict__ out) {
  const int wave = threadIdx.x >> 6;
  const int lane = threadIdx.x & 63;
  const int slot = lane >> 4;  // 0..3
  const int c = lane & 15;
  const int node = blockIdx.x * 4 + wave;
  const int beg = row_ptr[node];
  const int end = row_ptr[node + 1];

  float acc = 0.f;
  for (int it = beg; it < end; it += 8) {
    const int e0 = it + slot;
    const int e1 = it + 4 + slot;
    int2 m0 = make_int2(0, 0), m1 = make_int2(0, 0);
    if (e0 < end) m0 = meta[e0];
    if (e1 < end) m1 = meta[e1];
    const float v0 = h2[(size_t)m0.x * NUM_CLASSES + c];
    const float v1 = h2[(size_t)m1.x * NUM_CLASSES + c];
    acc = fmaf(__int_as_float(m0.y), v0, acc);
    acc = fmaf(__int_as_float(m1.y), v1, acc);
  }
  acc += __shfl_xor(acc, 32, 64);
  acc += __shfl_xor(acc, 16, 64);

  float mx = acc;
#pragma unroll
  for (int off = 8; off >= 1; off >>= 1) mx = fmaxf(mx, __shfl_xor(mx, off, 16));
  const float e = __expf(acc - mx);
  float s = e;
#pragma unroll
  for (int off = 8; off >= 1; off >>= 1) s += __shfl_xor(s, off, 16);
  if (lane < 16) out[(size_t)node * NUM_CLASSES + c] = e / s;
}

extern "C" void kernel_launch(void* const* d_in, const int* in_sizes, int n_in,
                              void* d_out, int out_size, void* d_ws,
                              size_t ws_size, hipStream_t stream) {
  const float* x = (const float*)d_in[0];
  const float* W1 = (const float*)d_in[1];
  const float* W2 = (const float*)d_in[2];
  const float* ew = (const float*)d_in[3];
  const int* esrc = (const int*)d_in[4];
  const int* edst = (const int*)d_in[5];
  float* out = (float*)d_out;

  _Float16* xw1 = (_Float16*)d_ws;
  float* h2 = (float*)(xw1 + (size_t)N_NODES * FILTERS);
  int* row_ptr = (int*)(h2 + (size_t)N_NODES * NUM_CLASSES);
  int* cursor = row_ptr + (N_NODES + 1);
  int* deg = cursor + N_NODES;
  int2* meta = (int2*)(((uintptr_t)(deg + N_NODES) + 15) & ~(uintptr_t)15);
  __bf16* w1th = (__bf16*)(meta + N_EDGES);
  __bf16* w1tl = w1th + D_FEAT * FILTERS;
  int* bsum = (int*)(w1tl + D_FEAT * FILTERS);

  hipMemsetAsync(deg, 0, N_NODES * sizeof(int), stream);
  hist_kernel<<<(N_EDGES + 255) / 256, 256, 0, stream>>>(edst, deg);
  scan_blocks_kernel<<<SCAN_NB, 256, 0, stream>>>(deg, row_ptr, bsum);
  scan_sums_kernel<<<1, 256, 0, stream>>>(bsum);
  scan_add_kernel<<<SCAN_NB, 256, 0, stream>>>(row_ptr, bsum, cursor);
  fill_kernel<<<(N_EDGES + 255) / 256, 256, 0, stream>>>(esrc, edst, ew,
                                                         cursor, meta);

  split_w1_kernel<<<(D_FEAT * FILTERS) / 256, 256, 0, stream>>>(W1, w1th, w1tl);
  dim3 g1((N_NODES + 127) / 128, FILTERS / 128);
  gemm1_mfma_kernel<<<g1, 256, 0, stream>>>(x, w1th, w1tl, xw1);

  gather1_gemm2_kernel<<<N_NODES / 4, 256, 0, stream>>>(xw1, row_ptr, meta, W2,
                                                        h2);

  gather2_softmax_kernel<<<N_NODES / 4, 256, 0, stream>>>(h2, row_ptr, meta,
                                                          out);
}